// Round 7
// baseline (360.998 us; speedup 1.0000x reference)
//
#include <hip/hip_runtime.h>
#include <cstdint>
#include <cstddef>

// Problem constants: B=64, N=1024, D=512, C=512, K=16, GAMMA=0.3, TEMP=0.07
#define INV_TEMP 14.285714285714285714f
#define GAMMA_ 0.3f

// A rows: 0..65535 = vpat (b*1024+n); 65536..65599 = cls; 65600..65663 = pad.
#define ROWS_PAD 65664

typedef short short8 __attribute__((ext_vector_type(8)));
typedef float floatx4 __attribute__((ext_vector_type(4)));

#if __has_builtin(__builtin_amdgcn_fmed3f)
#define MED3(v, hi, lo) __builtin_amdgcn_fmed3f((v), (hi), (lo))
#else
#define MED3(v, hi, lo) fmaxf(fminf((v), (hi)), (lo))
#endif

__device__ __forceinline__ unsigned short f2bf(float x) {
  unsigned int u = __float_as_uint(x);
  u += 0x7FFFu + ((u >> 16) & 1u);  // round-to-nearest-even
  return (unsigned short)(u >> 16);
}
__device__ __forceinline__ float bf2f(unsigned short h) {
  return __uint_as_float(((unsigned int)h) << 16);
}

// Branchless sorted-descending top-16 insert: 15 med3 + 1 max, depth-1 ILP.
__device__ __forceinline__ void insert16(float (&top)[16], float v) {
#pragma unroll
  for (int j = 15; j >= 1; --j) top[j] = MED3(v, top[j - 1], top[j]);
  top[0] = fmaxf(top[0], v);
}

// ---------------------------------------------------------------------------
// Prep: wave-per-row. wid<512: text row -> l2norm + bf16 hi/lo (B matrix).
// wid 512..639: Aext row (cls raw fp32 copy rows 0..63; zeros 64..127).
__global__ __launch_bounds__(256) void prep_kernel(
    const float* __restrict__ vcls, const float* __restrict__ text,
    unsigned short* __restrict__ Bh, unsigned short* __restrict__ Bl,
    float* __restrict__ Aext) {
  const int wid = blockIdx.x * 4 + (threadIdx.x >> 6);
  const int lane = threadIdx.x & 63;
  if (wid < 512) {
    const float* src = text + (size_t)wid * 512;
    const float4 v0 = ((const float4*)src)[lane];
    const float4 v1 = ((const float4*)src)[lane + 64];
    float ss = v0.x * v0.x + v0.y * v0.y + v0.z * v0.z + v0.w * v0.w +
               v1.x * v1.x + v1.y * v1.y + v1.z * v1.z + v1.w * v1.w;
#pragma unroll
    for (int off = 32; off; off >>= 1) ss += __shfl_xor(ss, off);
    const float scale = 1.0f / fmaxf(sqrtf(ss), 1e-12f);
    float a[8] = {v0.x * scale, v0.y * scale, v0.z * scale, v0.w * scale,
                  v1.x * scale, v1.y * scale, v1.z * scale, v1.w * scale};
    ushort4 h0, l0, h1, l1;
    h0.x = f2bf(a[0]); l0.x = f2bf(a[0] - bf2f(h0.x));
    h0.y = f2bf(a[1]); l0.y = f2bf(a[1] - bf2f(h0.y));
    h0.z = f2bf(a[2]); l0.z = f2bf(a[2] - bf2f(h0.z));
    h0.w = f2bf(a[3]); l0.w = f2bf(a[3] - bf2f(h0.w));
    h1.x = f2bf(a[4]); l1.x = f2bf(a[4] - bf2f(h1.x));
    h1.y = f2bf(a[5]); l1.y = f2bf(a[5] - bf2f(h1.y));
    h1.z = f2bf(a[6]); l1.z = f2bf(a[6] - bf2f(h1.z));
    h1.w = f2bf(a[7]); l1.w = f2bf(a[7] - bf2f(h1.w));
    ((ushort4*)(Bh + (size_t)wid * 512))[lane] = h0;
    ((ushort4*)(Bh + (size_t)wid * 512))[lane + 64] = h1;
    ((ushort4*)(Bl + (size_t)wid * 512))[lane] = l0;
    ((ushort4*)(Bl + (size_t)wid * 512))[lane + 64] = l1;
  } else {
    const int r = wid - 512;  // 0..127
    float4* dst = (float4*)(Aext + (size_t)r * 512);
    if (r < 64) {
      const float4* src = (const float4*)(vcls + (size_t)r * 512);
      dst[lane] = src[lane];
      dst[lane + 64] = src[lane + 64];
    } else {
      const float4 z = {0.f, 0.f, 0.f, 0.f};
      dst[lane] = z;
      dst[lane + 64] = z;
    }
  }
}

// ---------------------------------------------------------------------------
// Raw-A split-bf16 3-term MFMA GEMM, norms-in-kernel, fused softmax partials.
// logits[m][c] = (rawA[m][:] . Bnorm[c][:]) / ||rawA[m]||, K=512.
// Wave tiling: 4 waves x (32 rows x 128 cols) -> A converted ONCE per block
// (4096 elems, no cross-wave redundancy); B read 4x (cheap, no conversion).
// A LDS: two half-K arrays with 64-B rows (4 chunks/row, pos = g^((row>>1)&3))
// -> fragment ds_read_b128 has r5's measured-ZERO bank-conflict shape.
// |logit| <= 1 -> fixed softmax max 1.0 partial sumexp; pstat 4 slots (bn).
// XCD remap (verified r5): linear%8 = XCD; 4 bn-blocks of an A tile co-XCD.
__global__ __launch_bounds__(256) void gemm_raw_kernel(
    const float* __restrict__ Apat, const float* __restrict__ Aext,
    const unsigned short* __restrict__ Bhi, const unsigned short* __restrict__ Blo,
    float* __restrict__ Cout, float* __restrict__ pstat) {
  __shared__ __align__(16) unsigned char smem[32768];
  float* sA = (float*)smem;                              // 1024 chunks x 16 B
  unsigned short* sBh = (unsigned short*)(smem + 16384); // 8 KB
  unsigned short* sBl = (unsigned short*)(smem + 24576); // 8 KB
  const int tid = threadIdx.x;
  const int lane = tid & 63;
  const int w = tid >> 6;

  const int L = blockIdx.x;  // 0..2051
  int bm, bn;
  if (L < 2048) {
    const int xcd = L & 7;
    const int slot = L >> 3;
    bn = slot & 3;
    bm = (slot >> 2) * 8 + xcd;
  } else {
    bm = 512;
    bn = L - 2048;
  }
  const float* Abase = (bm < 512) ? (Apat + (size_t)bm * 128 * 512) : Aext;

  // A staging. LDS chunk c (16 B): h=c>>9 (k-half), r=(c>>2)&127, pos=c&3,
  // source k-chunk G = 4h + (pos ^ ((r>>1)&3)). Thread owns c = tid + q*256.
  unsigned aSrc[4];
#pragma unroll
  for (int q = 0; q < 4; ++q) {
    const int c = tid + q * 256;
    const int h = c >> 9, r = (c >> 2) & 127, pos = c & 3;
    const int G = 4 * h + (pos ^ ((r >> 1) & 3));
    aSrc[q] = (unsigned)r * 512u + (unsigned)G * 4u;  // float offset
  }
  // B staging (r5 pattern, 4 chunks/row, pos = g ^ ((row>>1)&3)).
  const int m0 = tid >> 2, g0 = (tid & 3) ^ ((m0 >> 1) & 3);
  const int i1 = 256 + tid;
  const int m1 = i1 >> 2, g1 = (i1 & 3) ^ ((m1 >> 1) & 3);
  const unsigned bO0 = (unsigned)(bn * 128 + m0) * 512u + (unsigned)g0 * 8u;
  const unsigned bO1 = (unsigned)(bn * 128 + m1) * 512u + (unsigned)g1 * 8u;

  const int l15 = lane & 15, kg = lane >> 4;
  // A fragment base chunk (e=0); e=1 chunk = base^1 (float idx ^4).
  int fA[2];
#pragma unroll
  for (int i = 0; i < 2; ++i) {
    const int ml = w * 32 + i * 16 + l15;
    const int pos0 = (2 * (kg & 1)) ^ ((ml >> 1) & 3);
    fA[i] = ((kg >> 1) * 512 + ml * 4 + pos0) * 4;  // float index
  }
  // B fragment offsets, 8 col-frags (full 128 cols per wave).
  int cB[8];
#pragma unroll
  for (int j = 0; j < 8; ++j) {
    const int nl = j * 16 + l15;
    cB[j] = (nl * 4 + (kg ^ ((nl >> 1) & 3))) * 8;  // ushort index
  }

  floatx4 acc[2][8] = {};
  float ssq[2] = {0.f, 0.f};

#define GL16(srcp, dstp)                                                        \
  __builtin_amdgcn_global_load_lds(                                             \
      (const __attribute__((address_space(1))) void*)(srcp),                    \
      (__attribute__((address_space(3))) void*)(dstp), 16, 0, 0)

  for (int ks = 0; ks < 16; ++ks) {
    const unsigned ko = (unsigned)ks * 32u;  // 32 elements
#pragma unroll
    for (int q = 0; q < 4; ++q)
      GL16(Abase + aSrc[q] + ko, (unsigned short*)sA + (w * 512 + q * 2048));
    GL16(Bhi + bO0 + ko, sBh + (unsigned)tid * 8u);
    GL16(Bhi + bO1 + ko, sBh + 2048u + (unsigned)tid * 8u);
    GL16(Blo + bO0 + ko, sBl + (unsigned)tid * 8u);
    GL16(Blo + bO1 + ko, sBl + 2048u + (unsigned)tid * 8u);
    __syncthreads();

    short8 ah[2], al[2];
#pragma unroll
    for (int i = 0; i < 2; ++i) {
      const float4 x0 = *(const float4*)(sA + fA[i]);
      const float4 x1 = *(const float4*)(sA + (fA[i] ^ 4));
      const float xs[8] = {x0.x, x0.y, x0.z, x0.w, x1.x, x1.y, x1.z, x1.w};
#pragma unroll
      for (int e = 0; e < 8; ++e) {
        const float f = xs[e];
        ssq[i] = fmaf(f, f, ssq[i]);
        const unsigned u = __float_as_uint(f) + 0x8000u;  // round-half-away
        ah[i][e] = (short)(u >> 16);
        al[i][e] = (short)(__float_as_uint(f - __uint_as_float(u & 0xFFFF0000u)) >> 16);
      }
    }
#pragma unroll
    for (int jq = 0; jq < 4; ++jq) {
      const short8 bh0 = *(const short8*)(sBh + cB[2 * jq]);
      const short8 bl0 = *(const short8*)(sBl + cB[2 * jq]);
      const short8 bh1 = *(const short8*)(sBh + cB[2 * jq + 1]);
      const short8 bl1 = *(const short8*)(sBl + cB[2 * jq + 1]);
#pragma unroll
      for (int i = 0; i < 2; ++i) {
        acc[i][2 * jq] = __builtin_amdgcn_mfma_f32_16x16x32_bf16(ah[i], bh0, acc[i][2 * jq], 0, 0, 0);
        acc[i][2 * jq] = __builtin_amdgcn_mfma_f32_16x16x32_bf16(ah[i], bl0, acc[i][2 * jq], 0, 0, 0);
        acc[i][2 * jq] = __builtin_amdgcn_mfma_f32_16x16x32_bf16(al[i], bh0, acc[i][2 * jq], 0, 0, 0);
        acc[i][2 * jq + 1] = __builtin_amdgcn_mfma_f32_16x16x32_bf16(ah[i], bh1, acc[i][2 * jq + 1], 0, 0, 0);
        acc[i][2 * jq + 1] = __builtin_amdgcn_mfma_f32_16x16x32_bf16(ah[i], bl1, acc[i][2 * jq + 1], 0, 0, 0);
        acc[i][2 * jq + 1] = __builtin_amdgcn_mfma_f32_16x16x32_bf16(al[i], bh1, acc[i][2 * jq + 1], 0, 0, 0);
      }
    }
    __syncthreads();
  }
#undef GL16

  // Row inverse norms: ssq[i] is k-partial for row (w*32+i*16+l15);
  // xor 16/32 sums over kg -> full-K ssq on every lane.
  float inv[2];
#pragma unroll
  for (int i = 0; i < 2; ++i) {
    float s = ssq[i];
    s += __shfl_xor(s, 16);
    s += __shfl_xor(s, 32);
    inv[i] = 1.0f / fmaxf(sqrtf(s), 1e-12f);
  }

  // C/D layout: col=lane&15, row=(lane>>4)*4+reg  [m89/m91 verified]
  const int quad = kg;
  const unsigned rowb0 = (unsigned)(bm * 128 + w * 32 + quad * 4);
  const unsigned colb0 = (unsigned)(bn * 128 + l15);
#pragma unroll
  for (int i = 0; i < 2; ++i) {
    // invA for acc rows quad*4+r lives in lane (kg=quad, l15=quad*4+r).
    float iv[4];
#pragma unroll
    for (int r = 0; r < 4; ++r) iv[r] = __shfl(inv[i], quad * 20 + r);
    float sc[8][4];
#pragma unroll
    for (int j = 0; j < 8; ++j)
#pragma unroll
      for (int r = 0; r < 4; ++r) sc[j][r] = acc[i][j][r] * iv[r];
#pragma unroll
    for (int j = 0; j < 8; ++j) {
      const unsigned col = colb0 + j * 16;
#pragma unroll
      for (int r = 0; r < 4; ++r)
        Cout[(size_t)(rowb0 + i * 16 + r) * 512 + col] = sc[j][r];
    }
    // Fused partial sumexp (fixed max 1.0) over this wave's 128 cols.
#pragma unroll
    for (int r = 0; r < 4; ++r) {
      float se = 0.f;
#pragma unroll
      for (int j = 0; j < 8; ++j) se += __expf((sc[j][r] - 1.0f) * INV_TEMP);
      se += __shfl_xor(se, 1);
      se += __shfl_xor(se, 2);
      se += __shfl_xor(se, 4);
      se += __shfl_xor(se, 8);
      if (l15 == 0) pstat[(size_t)(rowb0 + i * 16 + r) * 4 + bn] = se;
    }
  }
}

// ---------------------------------------------------------------------------
// Partial top-16 per (b,c) over an n-chunk of 64, in s = l*invT + LW[n]
// domain. LW from pstat (fixed-max-1.0): LW[m] = -(ln(sum_4 pstat) + invT).
__global__ __launch_bounds__(256) void topk_partial_kernel(
    const float* __restrict__ L, const float* __restrict__ pstat,
    float* __restrict__ cand) {
  const int b = blockIdx.x;
  const int c = blockIdx.y * 256 + threadIdx.x;
  const int nc = blockIdx.z;  // 0..15
  const size_t mb = (size_t)b * 1024 + (size_t)nc * 64;

  __shared__ float sLW[64];
  if (threadIdx.x < 64) {
    const float* p = pstat + (mb + threadIdx.x) * 4;
    const float S = p[0] + p[1] + p[2] + p[3];
    sLW[threadIdx.x] = -(__logf(S) + INV_TEMP);
  }
  __syncthreads();

  float top[16];
#pragma unroll
  for (int t = 0; t < 16; ++t) top[t] = -3.0e38f;
  const float* Lp = L + mb * 512 + c;
  for (int n0 = 0; n0 < 64; n0 += 8) {
    float s[8];
#pragma unroll
    for (int u = 0; u < 8; ++u)
      s[u] = fmaf(Lp[(size_t)(n0 + u) * 512], INV_TEMP, sLW[n0 + u]);
#pragma unroll
    for (int u = 0; u < 8; ++u) insert16(top, s[u]);
  }
  float* o = cand + ((size_t)b * 16 + nc) * 16 * 512 + c;
#pragma unroll
  for (int t = 0; t < 16; ++t) o[(size_t)t * 512] = top[t];
}

// Merge 16x16 s-candidates -> top-16 mean; fused aff_g from cls logit row.
__global__ __launch_bounds__(256) void topk_merge_kernel(
    const float* __restrict__ cand, const float* __restrict__ logits,
    const float* __restrict__ pstat, float* __restrict__ out) {
  const int gid = blockIdx.x * 256 + threadIdx.x;  // b*512 + c
  const int b = gid >> 9, c = gid & 511;
  const float* cb = cand + (size_t)b * 256 * 512 + c;
  float top[16];
#pragma unroll
  for (int t = 0; t < 16; ++t) top[t] = -3.0e38f;
  for (int kb = 0; kb < 16; ++kb) {
    float v[16];
#pragma unroll
    for (int j = 0; j < 16; ++j) v[j] = cb[(size_t)(kb * 16 + j) * 512];
#pragma unroll
    for (int j = 0; j < 16; ++j) insert16(top, v[j]);
  }
  float s = 0.f;
#pragma unroll
  for (int t = 0; t < 16; ++t) s += __expf(top[t]);
  const float* pc = pstat + ((size_t)65536 + b) * 4;
  const float S = pc[0] + pc[1] + pc[2] + pc[3];
  const float lg = logits[((size_t)65536 + b) * 512 + c];
  const float ag = __expf(fmaf(lg, INV_TEMP, -(__logf(S) + INV_TEMP)));
  out[gid] = GAMMA_ * ag + (1.0f - GAMMA_) * (s * (1.0f / 16.0f));
}

// ---------------------------------------------------------------------------
extern "C" void kernel_launch(void* const* d_in, const int* in_sizes, int n_in,
                              void* d_out, int out_size, void* d_ws, size_t ws_size,
                              hipStream_t stream) {
  const float* vcls = (const float*)d_in[0];  // [64,512]
  const float* vpat = (const float*)d_in[1];  // [64,1024,512]
  const float* text = (const float*)d_in[2];  // [512,512]
  float* out = (float*)d_out;                 // [64,512]

  char* p = (char*)d_ws;
  auto carve = [&](size_t bytes) -> char* {
    char* r = p;
    p += (bytes + 255) & ~(size_t)255;
    return r;
  };
  float* logits = (float*)carve((size_t)ROWS_PAD * 512 * 4);
  unsigned short* Bh = (unsigned short*)carve((size_t)512 * 512 * 2);
  unsigned short* Bl = (unsigned short*)carve((size_t)512 * 512 * 2);
  float* pstat = (float*)carve((size_t)ROWS_PAD * 4 * 4);
  float* Aext = (float*)carve((size_t)128 * 512 * 4);
  float* cand = (float*)carve((size_t)64 * 16 * 16 * 512 * 4);
  if ((size_t)(p - (char*)d_ws) > ws_size) return;

  prep_kernel<<<160, 256, 0, stream>>>(vcls, text, Bh, Bl, Aext);
  gemm_raw_kernel<<<2052, 256, 0, stream>>>(vpat, Aext, Bh, Bl, logits, pstat);
  topk_partial_kernel<<<dim3(64, 2, 16), 256, 0, stream>>>(logits, pstat, cand);
  topk_merge_kernel<<<128, 256, 0, stream>>>(cand, logits, pstat, out);
}